// Round 8
// baseline (186.819 us; speedup 1.0000x reference)
//
#include <hip/hip_runtime.h>

#define LAMC    10000.0f
#define INV_LAM 1e-4f
#define EPSC    1e-12f
#define TOLC    1e-6f
#define BLK     256
#define WPB     (BLK / 64)   // waves per block
#define GRID    2048         // 8 blocks/CU on 256 CUs; ntiles/GRID tiles per block

__device__ __forceinline__ float frcp(float x)  { return __builtin_amdgcn_rcpf(x); }
__device__ __forceinline__ float frsq(float x)  { return __builtin_amdgcn_rsqf(x); }
__device__ __forceinline__ float fsqrt_(float x){ return __builtin_amdgcn_sqrtf(x); }

// sign(phi(t)) without sqrt/div: phi = L - R*sqrt(q), q >= EPS > 0
__device__ __forceinline__ bool phi_pos(float t, float A, float p, float N, float b) {
    float q  = fmaxf(fmaf(t, fmaf(t, A, -2.0f * p), N), EPSC);
    float L  = fmaf(-t, A, p);        // p - t*A   (U_MAX = 1)
    float R  = fmaf(t, INV_LAM, b);   // b + t/LAM
    float L2 = L * L;
    float Rq = (R * R) * q;
    return (R < 0.0f) ? ((L >= 0.0f) || (L2 < Rq))
                      : ((L >  0.0f) && (L2 > Rq));
}

// branch-3 solve, proven tight bracket; 12 bisect + 5 safeguarded Newton.
// Numerics identical to the passing round-6 kernel.
__device__ __forceinline__ float2 heavy_solve(float ux, float uy,
                                              float ax, float ay, float b) {
    float A = fmaf(ax, ax, ay * ay);
    float p = fmaf(ax, ux, ay * uy);
    float N = fmaf(ux, ux, uy * uy);
    float t3;
    if (phi_pos(0.0f, A, p, N, b)) {
        float lo, hi;
        if (p > 0.0f) {
            float tA = p * frcp(fmaxf(A, 1e-30f));
            if (fmaf(tA, INV_LAM, b) >= 0.0f) { lo = 0.0f; hi = tA; }
            else                              { lo = tA;  hi = -LAMC * b; }
        } else {
            lo = 0.0f; hi = -LAMC * b;
        }
        #pragma unroll 1
        for (int k = 0; k < 12; ++k) {
            float mid = 0.5f * (lo + hi);
            bool pos = phi_pos(mid, A, p, N, b);
            lo = pos ? mid : lo;
            hi = pos ? hi : mid;
        }
        t3 = 0.5f * (lo + hi);
        #pragma unroll
        for (int k = 0; k < 5; ++k) {          // safeguarded Newton
            float q   = fmaxf(fmaf(t3, fmaf(t3, A, -2.0f * p), N), EPSC);
            float nrm = fsqrt_(q);
            float R   = fmaf(t3, INV_LAM, b);
            float f   = fmaf(-t3, A, p) - R * nrm;
            float df  = -A - nrm * INV_LAM - R * fmaf(t3, A, -p) * frcp(nrm);
            df = (fabsf(df) > 1e-8f) ? df : -1e-8f;
            bool fp = f > 0.0f;
            lo = fp ? t3 : lo;
            hi = fp ? hi : t3;
            t3 = fminf(fmaxf(t3 - f * frcp(df), lo), hi);
        }
    } else {
        // reference: bisection collapses to 0, then 3 unclamped Newton steps
        t3 = 0.0f;
        #pragma unroll
        for (int k = 0; k < 3; ++k) {
            float q   = fmaxf(fmaf(t3, fmaf(t3, A, -2.0f * p), N), EPSC);
            float nrm = fsqrt_(q);
            float R   = fmaf(t3, INV_LAM, b);
            float f   = fmaf(-t3, A, p) - R * nrm;
            float df  = -A - nrm * INV_LAM - R * fmaf(t3, A, -p) * frcp(nrm);
            df = (fabsf(df) > 1e-8f) ? df : -1e-8f;
            t3 = t3 - f * frcp(df);
        }
    }
    float q3  = fmaxf(fmaf(t3, fmaf(t3, A, -2.0f * p), N), EPSC);
    float k3  = fmaxf(fsqrt_(q3), 1.0f);
    float inv = frcp(k3);
    return make_float2(fmaf(-t3, ax, ux) * inv, fmaf(-t3, ay, uy) * inv);
}

// easy paths; returns true if heavy. Also exports (ax,ay,b) for LDS staging.
__device__ __forceinline__ bool easy_row(float ux, float uy,
                                         float px, float py, float vx, float vy,
                                         float& ox, float& oy,
                                         float& axo, float& ayo, float& bo) {
    float ax = -2.0f * px, ay = -2.0f * py;
    float h  = fmaf(px, px, py * py) - 1.0f;
    float b  = fmaf(2.0f, h, -2.0f * fmaf(px, vx, py * vy));
    axo = ax; ayo = ay; bo = b;
    float A  = fmaf(ax, ax, ay * ay);
    float p  = fmaf(ax, ux, ay * uy);
    float N  = fmaf(ux, ux, uy * uy);
    float s1 = fminf(1.0f, frsq(fmaxf(N, EPSC)));   // min(1, 1/|u|)
    float u1x = ux * s1, u1y = uy * s1;
    ox = u1x; oy = u1y;
    if (fmaf(ax, u1x, ay * u1y) <= b + TOLC) return false;
    float t2  = LAMC * (p - b) * frcp(fmaf(LAMC, A, 1.0f));
    float u2x = fmaf(-t2, ax, ux), u2y = fmaf(-t2, ay, uy);
    if (t2 >= -TOLC && fmaf(u2x, u2x, u2y * u2y) <= 1.0f + TOLC) {
        ox = u2x; oy = u2y; return false;
    }
    return true;
}

struct Tile { float4 u, o0, o1, o2; };

__device__ __forceinline__ Tile load_tile(const float4* __restrict__ u4,
                                          const float4* __restrict__ obs4,
                                          int p, bool v) {
    Tile t;
    float4 z = make_float4(0.f, 0.f, 0.f, 0.f);
    t.u = z; t.o0 = z; t.o1 = z; t.o2 = z;
    if (v) {
        t.u  = u4[p];
        t.o0 = obs4[3 * p];
        t.o1 = obs4[3 * p + 1];
        t.o2 = obs4[3 * p + 2];
    }
    return t;
}

// Persistent grid + register prefetch of the next tile; heavy operands staged
// into compacted LDS (no global re-gather on the heavy critical path).
__global__ __launch_bounds__(BLK) void cbf_kernel(const float4* __restrict__ u4,
                                                  const float4* __restrict__ obs4,
                                                  float4* __restrict__ out4,
                                                  int npair, int ntiles) {
    __shared__ float  sux[WPB][128], suy[WPB][128];
    __shared__ float  sax[WPB][128], say[WPB][128], sb[WPB][128];
    __shared__ short  sid[WPB][128];
    __shared__ float2 sres[WPB][128];

    int tid  = threadIdx.x;
    int wave = tid >> 6;
    int lane = tid & 63;
    unsigned long long ltmask = (1ull << lane) - 1ull;

    int tile = blockIdx.x;
    int p    = tile * BLK + tid;
    Tile cur = load_tile(u4, obs4, p, p < npair);

    #pragma unroll 1
    while (true) {
        int nt = tile + GRID;
        bool has_next = nt < ntiles;
        int pn = nt * BLK + tid;
        Tile nxt = load_tile(u4, obs4, pn, has_next && pn < npair);  // in flight

        // ---- process cur ----
        bool valid = p < npair;
        float4 r = make_float4(0.f, 0.f, 0.f, 0.f);
        float ax0, ay0, bb0, ax1, ay1, bb1;
        bool h0 = false, h1 = false;
        if (valid) {
            h0 = easy_row(cur.u.x, cur.u.y, cur.o0.z, cur.o0.w, cur.o1.x, cur.o1.y,
                          r.x, r.y, ax0, ay0, bb0);
            h1 = easy_row(cur.u.z, cur.u.w, cur.o2.x, cur.o2.y, cur.o2.z, cur.o2.w,
                          r.z, r.w, ax1, ay1, bb1);
        }

        // wave-local ballot compaction with payload staging
        unsigned long long m0 = __ballot(h0);
        unsigned long long m1 = __ballot(h1);
        int c0  = __popcll(m0);
        int tot = c0 + __popcll(m1);
        if (h0) {
            int j = __popcll(m0 & ltmask);
            sux[wave][j] = cur.u.x; suy[wave][j] = cur.u.y;
            sax[wave][j] = ax0;     say[wave][j] = ay0;  sb[wave][j] = bb0;
            sid[wave][j] = (short)(2 * lane);
        }
        if (h1) {
            int j = c0 + __popcll(m1 & ltmask);
            sux[wave][j] = cur.u.z; suy[wave][j] = cur.u.w;
            sax[wave][j] = ax1;     say[wave][j] = ay1;  sb[wave][j] = bb1;
            sid[wave][j] = (short)(2 * lane + 1);
        }
        __threadfence_block();   // wave lockstep + lgkmcnt orders LDS w->r

        #pragma unroll 1
        for (int j = lane; j < tot; j += 64) {
            float2 s = heavy_solve(sux[wave][j], suy[wave][j],
                                   sax[wave][j], say[wave][j], sb[wave][j]);
            sres[wave][sid[wave][j]] = s;
        }
        __threadfence_block();

        if (h0) { float2 s = sres[wave][2 * lane];     r.x = s.x; r.y = s.y; }
        if (h1) { float2 s = sres[wave][2 * lane + 1]; r.z = s.x; r.w = s.y; }
        if (valid) out4[p] = r;
        // ---- end process ----

        if (!has_next) break;
        cur = nxt; tile = nt; p = pn;
    }
}

extern "C" void kernel_launch(void* const* d_in, const int* in_sizes, int n_in,
                              void* d_out, int out_size, void* d_ws, size_t ws_size,
                              hipStream_t stream) {
    const float* u_nom = (const float*)d_in[0];
    const float* obs   = (const float*)d_in[1];
    float* out = (float*)d_out;
    int rows   = in_sizes[0] / 2;                 // B
    int npair  = rows / 2;
    int ntiles = (npair + BLK - 1) / BLK;
    int blocks = (ntiles < GRID) ? ntiles : GRID;
    cbf_kernel<<<blocks, BLK, 0, stream>>>((const float4*)u_nom,
                                           (const float4*)obs,
                                           (float4*)out, npair, ntiles);
}

// Round 9
// 182.761 us; speedup vs baseline: 1.0222x; 1.0222x over previous
//
#include <hip/hip_runtime.h>

#define LAMC    10000.0f
#define INV_LAM 1e-4f
#define EPSC    1e-12f
#define TOLC    1e-6f
#define BLK     256

__device__ __forceinline__ float frcp(float x)  { return __builtin_amdgcn_rcpf(x); }
__device__ __forceinline__ float frsq(float x)  { return __builtin_amdgcn_rsqf(x); }
__device__ __forceinline__ float fsqrt_(float x){ return __builtin_amdgcn_sqrtf(x); }

// sign(phi(t)) without sqrt/div: phi = L - R*sqrt(q), q >= EPS > 0
__device__ __forceinline__ bool phi_pos(float t, float A, float p, float N, float b) {
    float q  = fmaxf(fmaf(t, fmaf(t, A, -2.0f * p), N), EPSC);
    float L  = fmaf(-t, A, p);        // p - t*A   (U_MAX = 1)
    float R  = fmaf(t, INV_LAM, b);   // b + t/LAM
    float L2 = L * L;
    float Rq = (R * R) * q;
    return (R < 0.0f) ? ((L >= 0.0f) || (L2 < Rq))
                      : ((L >  0.0f) && (L2 > Rq));
}

// branch-3 solve with proven tight bracket (phi has a unique sign change):
//  - p>0, R(p/A)>=0 : root in (0, p/A];  - p>0, R(p/A)<0 : root in (p/A, -lam*b)
//  - p<=0 (=> b<0)  : root in (0, -lam*b)
// 12 bisections + 5 safeguarded Newton. Numerics identical to passing round 6.
__device__ __forceinline__ float2 heavy_solve(float ux, float uy,
                                              float ax, float ay, float b) {
    float A = fmaf(ax, ax, ay * ay);
    float p = fmaf(ax, ux, ay * uy);
    float N = fmaf(ux, ux, uy * uy);
    float t3;
    if (phi_pos(0.0f, A, p, N, b)) {
        float lo, hi;
        if (p > 0.0f) {
            float tA = p * frcp(fmaxf(A, 1e-30f));
            if (fmaf(tA, INV_LAM, b) >= 0.0f) { lo = 0.0f; hi = tA; }
            else                              { lo = tA;  hi = -LAMC * b; }
        } else {
            lo = 0.0f; hi = -LAMC * b;
        }
        #pragma unroll 1
        for (int k = 0; k < 12; ++k) {
            float mid = 0.5f * (lo + hi);
            bool pos = phi_pos(mid, A, p, N, b);
            lo = pos ? mid : lo;
            hi = pos ? hi : mid;
        }
        t3 = 0.5f * (lo + hi);
        #pragma unroll
        for (int k = 0; k < 5; ++k) {          // safeguarded Newton
            float q   = fmaxf(fmaf(t3, fmaf(t3, A, -2.0f * p), N), EPSC);
            float nrm = fsqrt_(q);
            float R   = fmaf(t3, INV_LAM, b);
            float f   = fmaf(-t3, A, p) - R * nrm;
            float df  = -A - nrm * INV_LAM - R * fmaf(t3, A, -p) * frcp(nrm);
            df = (fabsf(df) > 1e-8f) ? df : -1e-8f;
            bool fp = f > 0.0f;
            lo = fp ? t3 : lo;
            hi = fp ? hi : t3;
            t3 = fminf(fmaxf(t3 - f * frcp(df), lo), hi);
        }
    } else {
        // reference: bisection collapses to 0, then 3 unclamped Newton steps
        t3 = 0.0f;
        #pragma unroll
        for (int k = 0; k < 3; ++k) {
            float q   = fmaxf(fmaf(t3, fmaf(t3, A, -2.0f * p), N), EPSC);
            float nrm = fsqrt_(q);
            float R   = fmaf(t3, INV_LAM, b);
            float f   = fmaf(-t3, A, p) - R * nrm;
            float df  = -A - nrm * INV_LAM - R * fmaf(t3, A, -p) * frcp(nrm);
            df = (fabsf(df) > 1e-8f) ? df : -1e-8f;
            t3 = t3 - f * frcp(df);
        }
    }
    float q3  = fmaxf(fmaf(t3, fmaf(t3, A, -2.0f * p), N), EPSC);
    float k3  = fmaxf(fsqrt_(q3), 1.0f);
    float inv = frcp(k3);
    return make_float2(fmaf(-t3, ax, ux) * inv, fmaf(-t3, ay, uy) * inv);
}

// easy paths; returns true if heavy (branch 3). Exports (ax,ay,b).
__device__ __forceinline__ bool easy_row(float ux, float uy,
                                         float px, float py, float vx, float vy,
                                         float& ox, float& oy,
                                         float& axo, float& ayo, float& bo) {
    float ax = -2.0f * px, ay = -2.0f * py;
    float h  = fmaf(px, px, py * py) - 1.0f;
    float b  = fmaf(2.0f, h, -2.0f * fmaf(px, vx, py * vy));
    axo = ax; ayo = ay; bo = b;
    float A  = fmaf(ax, ax, ay * ay);
    float p  = fmaf(ax, ux, ay * uy);
    float N  = fmaf(ux, ux, uy * uy);
    float s1 = fminf(1.0f, frsq(fmaxf(N, EPSC)));   // min(1, 1/|u|)
    float u1x = ux * s1, u1y = uy * s1;
    ox = u1x; oy = u1y;
    if (fmaf(ax, u1x, ay * u1y) <= b + TOLC) return false;
    float t2  = LAMC * (p - b) * frcp(fmaf(LAMC, A, 1.0f));
    float u2x = fmaf(-t2, ax, ux), u2y = fmaf(-t2, ay, uy);
    if (t2 >= -TOLC && fmaf(u2x, u2x, u2y * u2y) <= 1.0f + TOLC) {
        ox = u2x; oy = u2y; return false;
    }
    return true;
}

// Fully inline, stall-free structure (R1 shape, 96% VALUBusy) with the cheap
// fast-math solver (R6 numerics). No LDS / ballot / atomics — the exec-mask
// heavy bodies cost less than the compaction stall they'd avoid.
__global__ __launch_bounds__(BLK) void cbf_kernel(const float4* __restrict__ u4,
                                                  const float4* __restrict__ obs4,
                                                  float4* __restrict__ out4,
                                                  int npair) {
    int i = blockIdx.x * BLK + threadIdx.x;
    if (i >= npair) return;
    float4 u  = u4[i];
    float4 o0 = obs4[3 * i + 0];
    float4 o1 = obs4[3 * i + 1];
    float4 o2 = obs4[3 * i + 2];
    // row 2i:   p=(o0.z,o0.w)  v=(o1.x,o1.y)
    // row 2i+1: p=(o2.x,o2.y)  v=(o2.z,o2.w)
    float4 r;
    float ax0, ay0, bb0, ax1, ay1, bb1;
    bool h0 = easy_row(u.x, u.y, o0.z, o0.w, o1.x, o1.y, r.x, r.y, ax0, ay0, bb0);
    bool h1 = easy_row(u.z, u.w, o2.x, o2.y, o2.z, o2.w, r.z, r.w, ax1, ay1, bb1);
    if (h0) { float2 s = heavy_solve(u.x, u.y, ax0, ay0, bb0); r.x = s.x; r.y = s.y; }
    if (h1) { float2 s = heavy_solve(u.z, u.w, ax1, ay1, bb1); r.z = s.x; r.w = s.y; }
    out4[i] = r;
}

extern "C" void kernel_launch(void* const* d_in, const int* in_sizes, int n_in,
                              void* d_out, int out_size, void* d_ws, size_t ws_size,
                              hipStream_t stream) {
    const float* u_nom = (const float*)d_in[0];
    const float* obs   = (const float*)d_in[1];
    float* out = (float*)d_out;
    int rows   = in_sizes[0] / 2;     // B
    int npair  = rows / 2;            // 2 rows per thread
    int blocks = (npair + BLK - 1) / BLK;
    cbf_kernel<<<blocks, BLK, 0, stream>>>((const float4*)u_nom,
                                           (const float4*)obs,
                                           (float4*)out, npair);
}